// Round 6
// baseline (477.502 us; speedup 1.0000x reference)
//
#include <hip/hip_runtime.h>
#include <hip/hip_bf16.h>

typedef __bf16 bf16_t;
typedef __attribute__((ext_vector_type(8))) __bf16 bf16x8;
typedef __attribute__((ext_vector_type(4))) __bf16 bf16x4;
typedef __attribute__((ext_vector_type(4))) float f32x4;

#define GAS __attribute__((address_space(1)))
#define LAS __attribute__((address_space(3)))

__device__ __forceinline__ void async_copy16(const bf16_t* g, bf16_t* l) {
    __builtin_amdgcn_global_load_lds((const GAS void*)g, (LAS void*)l, 16, 0, 0);
}

// ---------------------------------------------------------------------------
// Weight convert: 4 fp32 weight matrices (1M elems each) -> contiguous bf16.
// ---------------------------------------------------------------------------
__global__ __launch_bounds__(256) void wconvert_kernel(
    const float* __restrict__ w0, const float* __restrict__ w1,
    const float* __restrict__ w2, const float* __restrict__ w3,
    bf16_t* __restrict__ dst)
{
    int which = blockIdx.x >> 9;
    const float* src = which == 0 ? w0 : which == 1 ? w1 : which == 2 ? w2 : w3;
    int i = ((blockIdx.x & 511) * 256 + threadIdx.x) * 8;
    f32x4 f0 = *(const f32x4*)(src + i);
    f32x4 f1 = *(const f32x4*)(src + i + 4);
    bf16x8 v;
#pragma unroll
    for (int j = 0; j < 4; j++) { v[j] = (bf16_t)f0[j]; v[4 + j] = (bf16_t)f1[j]; }
    *(bf16x8*)&dst[(size_t)which * 1048576 + i] = v;
}

// ---------------------------------------------------------------------------
// Mask bit-pack: [4,1,2048,2048] int32 (0/1) -> bits. One wave packs 64 ints.
// ---------------------------------------------------------------------------
__global__ __launch_bounds__(256) void pack_mask_kernel(
    const int* __restrict__ mask, unsigned long long* __restrict__ out)
{
    int i = blockIdx.x * 256 + threadIdx.x;
    unsigned long long bits = __ballot(mask[i] != 0);
    if ((threadIdx.x & 63) == 0) out[i >> 6] = bits;
}

// ---------------------------------------------------------------------------
// Fused Q/K/V projection GEMM: grid.z selects input/weight/bias/output.
// A fp32 (register-staged + converted), W bf16 (DMA-staged).
// LDS double-buffered, ONE barrier per K-tile; A-loads prefetched 2 tiles,
// W-DMA issued 1 tile ahead (latency overlapped with compute).
// z=0,1: out bf16 [b,h,s,dk] (Q,K). z=2: out bf16 [b,h,dk,s] (V^T, operand swap).
// ---------------------------------------------------------------------------
__global__ __launch_bounds__(256, 2) void qkv_gemm(
    const float* __restrict__ Aq, const float* __restrict__ Ak,
    const float* __restrict__ Av, const bf16_t* __restrict__ Wall,
    const float* __restrict__ bq, const float* __restrict__ bk,
    const float* __restrict__ bv,
    bf16_t* __restrict__ Qb, bf16_t* __restrict__ Kb, bf16_t* __restrict__ Vtb)
{
    const int z = blockIdx.z;
    const float*  A    = z == 0 ? Aq : z == 1 ? Ak : Av;
    const bf16_t* W    = Wall + (size_t)z * 1048576;
    const float*  bias = z == 0 ? bq : z == 1 ? bk : bv;
    bf16_t*       out  = z == 0 ? Qb : z == 1 ? Kb : Vtb;

    __shared__ __align__(16) bf16_t Ab[2][128 * 32];
    __shared__ __align__(16) bf16_t Wb[2][128 * 32];

    const int tid  = threadIdx.x;
    const int wave = tid >> 6, lane = tid & 63;
    const int quad = lane >> 4, lq = lane & 15;
    const int wm = wave >> 1, wn = wave & 1;
    const int tm = blockIdx.x * 128, tn = blockIdx.y * 128;
    const int K = 1024;

    // fp32 A staging: thread -> (row=tid>>3 [+32*i], chunk=tid&7 of 4 floats)
    const int r0f = tid >> 3, c0f = tid & 7;
    const float* gA = A + (size_t)(tm + r0f) * K + c0f * 4;
    // W DMA: wave stages rows [wave*32, wave*32+32)
    const bf16_t* gW0 = W + (size_t)(tn + wave * 32 + (lane >> 2)) * K + (lane & 3) * 8;
    const bf16_t* gW1 = gW0 + (size_t)16 * K;
    const int wd0 = (wave * 32) * 32, wd1 = (wave * 32 + 16) * 32;

    f32x4 areg[4];
#define LOAD_A(k) { _Pragma("unroll") \
    for (int i = 0; i < 4; i++) areg[i] = *(const f32x4*)(gA + (size_t)(32 * i) * K + (k)); }
#define WRITE_A(buf) { _Pragma("unroll") \
    for (int i = 0; i < 4; i++) { bf16x4 v_; _Pragma("unroll") \
        for (int j = 0; j < 4; j++) v_[j] = (bf16_t)areg[i][j]; \
        *(bf16x4*)&Ab[buf][(r0f + 32 * i) * 32 + c0f * 4] = v_; } }
#define DMA_W(k, buf) { async_copy16(gW0 + (k), &Wb[buf][wd0]); \
                        async_copy16(gW1 + (k), &Wb[buf][wd1]); }

    f32x4 acc[4][4] = {};

    LOAD_A(0);
    WRITE_A(0);
    DMA_W(0, 0);
    LOAD_A(32);
    __syncthreads();

    for (int t = 0; t < 32; ++t) {
        if (t < 31) { WRITE_A((t + 1) & 1); DMA_W((t + 1) * 32, (t + 1) & 1); }
        if (t < 30) { LOAD_A((t + 2) * 32); }

        const int buf = t & 1;
        bf16x8 af[4], bfr[4];
#pragma unroll
        for (int i = 0; i < 4; i++) {
            af[i]  = *(const bf16x8*)&Ab[buf][(wm * 64 + i * 16 + lq) * 32 + quad * 8];
            bfr[i] = *(const bf16x8*)&Wb[buf][(wn * 64 + i * 16 + lq) * 32 + quad * 8];
        }
        if (z == 2) {
#pragma unroll
            for (int i = 0; i < 4; i++)
#pragma unroll
                for (int j = 0; j < 4; j++)
                    acc[i][j] = __builtin_amdgcn_mfma_f32_16x16x32_bf16(bfr[j], af[i], acc[i][j], 0, 0, 0);
        } else {
#pragma unroll
            for (int i = 0; i < 4; i++)
#pragma unroll
                for (int j = 0; j < 4; j++)
                    acc[i][j] = __builtin_amdgcn_mfma_f32_16x16x32_bf16(af[i], bfr[j], acc[i][j], 0, 0, 0);
        }
        __syncthreads();
    }

#pragma unroll
    for (int i = 0; i < 4; i++)
#pragma unroll
        for (int j = 0; j < 4; j++)
#pragma unroll
            for (int r = 0; r < 4; r++) {
                float v = acc[i][j][r];
                if (z <= 1) {
                    int row = tm + wm * 64 + i * 16 + quad * 4 + r;  // m = b*2048+s
                    int col = tn + wn * 64 + j * 16 + lq;            // n -> (h,dk)
                    v += bias[col];
                    int b = row >> 11, s = row & 2047;
                    int h = col >> 6,  dk = col & 63;
                    out[(((size_t)(b * 16 + h) * 2048 + s) << 6) + dk] = (bf16_t)v;
                } else {
                    int n = tn + wn * 64 + j * 16 + quad * 4 + r;    // W row
                    int m = tm + wm * 64 + i * 16 + lq;              // X row
                    v += bias[n];
                    int b = m >> 11, s = m & 2047;
                    int h = n >> 6,  dk = n & 63;
                    out[((size_t)((b * 16 + h) * 64 + dk) << 11) + s] = (bf16_t)v;
                }
            }
#undef LOAD_A
#undef WRITE_A
#undef DMA_W
}

// ---------------------------------------------------------------------------
// Output projection: A bf16 (X), W bf16, out fp32 row-major [8192][1024].
// Both operands DMA-staged; dbuf, one barrier/iter, DMA issued 1 tile ahead.
// ---------------------------------------------------------------------------
__global__ __launch_bounds__(256, 2) void gemm_o(
    const bf16_t* __restrict__ A, const bf16_t* __restrict__ W,
    const float* __restrict__ bias, float* __restrict__ out)
{
    __shared__ __align__(16) bf16_t Ab[2][128 * 32];
    __shared__ __align__(16) bf16_t Wb[2][128 * 32];

    const int tid  = threadIdx.x;
    const int wave = tid >> 6, lane = tid & 63;
    const int quad = lane >> 4, lq = lane & 15;
    const int wm = wave >> 1, wn = wave & 1;
    const int tm = blockIdx.x * 128, tn = blockIdx.y * 128;
    const int K = 1024;

    const bf16_t* gA0 = A + (size_t)(tm + wave * 32 + (lane >> 2)) * K + (lane & 3) * 8;
    const bf16_t* gA1 = gA0 + (size_t)16 * K;
    const bf16_t* gW0 = W + (size_t)(tn + wave * 32 + (lane >> 2)) * K + (lane & 3) * 8;
    const bf16_t* gW1 = gW0 + (size_t)16 * K;
    const int d0 = (wave * 32) * 32, d1 = (wave * 32 + 16) * 32;

#define DMA_T(k, buf) { async_copy16(gA0 + (k), &Ab[buf][d0]); \
                        async_copy16(gA1 + (k), &Ab[buf][d1]); \
                        async_copy16(gW0 + (k), &Wb[buf][d0]); \
                        async_copy16(gW1 + (k), &Wb[buf][d1]); }

    f32x4 acc[4][4] = {};

    DMA_T(0, 0);
    __syncthreads();

    for (int t = 0; t < 32; ++t) {
        if (t < 31) DMA_T((t + 1) * 32, (t + 1) & 1);

        const int buf = t & 1;
        bf16x8 af[4], bfr[4];
#pragma unroll
        for (int i = 0; i < 4; i++) {
            af[i]  = *(const bf16x8*)&Ab[buf][(wm * 64 + i * 16 + lq) * 32 + quad * 8];
            bfr[i] = *(const bf16x8*)&Wb[buf][(wn * 64 + i * 16 + lq) * 32 + quad * 8];
        }
#pragma unroll
        for (int i = 0; i < 4; i++)
#pragma unroll
            for (int j = 0; j < 4; j++)
                acc[i][j] = __builtin_amdgcn_mfma_f32_16x16x32_bf16(af[i], bfr[j], acc[i][j], 0, 0, 0);
        __syncthreads();
    }

#pragma unroll
    for (int i = 0; i < 4; i++)
#pragma unroll
        for (int j = 0; j < 4; j++)
#pragma unroll
            for (int r = 0; r < 4; r++) {
                int row = tm + wm * 64 + i * 16 + quad * 4 + r;
                int col = tn + wn * 64 + j * 16 + lq;
                out[(size_t)row * 1024 + col] = acc[i][j][r] + bias[col];
            }
#undef DMA_T
}

// ---------------------------------------------------------------------------
// Flash attention, S^T form. grid (S/128, B*H), 4 waves, wave = 32 q-rows.
// LDS double-buffered K/V, ONE barrier per 32-key iter, global loads + mask
// prefetched a full iteration ahead.
// ---------------------------------------------------------------------------
#define LDK 72
#define LDV 40
#define LDP 40

__global__ __launch_bounds__(256, 2) void attn_kernel(
    const bf16_t* __restrict__ Q, const bf16_t* __restrict__ Kh,
    const bf16_t* __restrict__ Vt, const unsigned int* __restrict__ mp,
    bf16_t* __restrict__ X)
{
    __shared__ __align__(16) bf16_t KbL[2][32 * LDK];
    __shared__ __align__(16) bf16_t VbL[2][64 * LDV];
    __shared__ __align__(16) bf16_t Pls[4][32 * LDP];

    const int tid  = threadIdx.x;
    const int wave = tid >> 6, lane = tid & 63;
    const int quad = lane >> 4, lq = lane & 15;
    const int bh = blockIdx.y, b = bh >> 4, h = bh & 15;
    const int qw = blockIdx.x * 128 + wave * 32;

    // Q fragments for two q-sets (B-operand for S^T: n=lq -> q row)
    bf16x8 qf[2][2];
#pragma unroll
    for (int s = 0; s < 2; s++) {
        const bf16_t* qptr = Q + ((size_t)bh * 2048 + qw + s * 16 + lq) * 64 + quad * 8;
        qf[s][0] = *(const bf16x8*)qptr;
        qf[s][1] = *(const bf16x8*)(qptr + 32);
    }

    f32x4 o[2][4] = {};
    float lsum[2] = {0.f, 0.f};

    const int kr = tid >> 3, kc = tid & 7;   // K stage: 32 rows x 8 chunks
    const int vr = tid >> 2, vc = tid & 3;   // V stage: 64 rows x 4 chunks
    const bf16_t* gK = Kh + ((size_t)bh * 2048 + kr) * 64 + kc * 8;
    const bf16_t* gV = Vt + ((size_t)bh * 64 + vr) * 2048 + vc * 8;
    const unsigned int* mrow0 = mp + ((size_t)(b << 11) + qw + lq) * 64;
    const unsigned int* mrow1 = mrow0 + 16 * 64;

    // prologue: tile 0 into buf 0; prefetch tile 1 into regs
    bf16x8 kst = *(const bf16x8*)gK;
    bf16x8 vst = *(const bf16x8*)gV;
    *(bf16x8*)&KbL[0][kr * LDK + kc * 8] = kst;
    *(bf16x8*)&VbL[0][vr * LDV + vc * 8] = vst;
    kst = *(const bf16x8*)(gK + 2048);
    vst = *(const bf16x8*)(gV + 32);
    unsigned int mw0 = mrow0[0], mw1 = mrow1[0];
    __syncthreads();

    for (int t = 0; t < 64; ++t) {
        if (t < 63) {
            *(bf16x8*)&KbL[(t + 1) & 1][kr * LDK + kc * 8] = kst;
            *(bf16x8*)&VbL[(t + 1) & 1][vr * LDV + vc * 8] = vst;
        }
        if (t < 62) {
            kst = *(const bf16x8*)(gK + (size_t)(t + 2) * 2048);
            vst = *(const bf16x8*)(gV + (size_t)(t + 2) * 32);
        }
        unsigned int w0 = mw0, w1 = mw1;
        if (t < 63) { mw0 = mrow0[t + 1]; mw1 = mrow1[t + 1]; }

        const bf16_t* Kc = &KbL[t & 1][0];
        const bf16_t* Vc = &VbL[t & 1][0];
        bf16_t* pb = &Pls[wave][0];

        bf16x8 kf[2][2];
#pragma unroll
        for (int nt = 0; nt < 2; nt++) {
            kf[nt][0] = *(const bf16x8*)&Kc[(nt * 16 + lq) * LDK + quad * 8];
            kf[nt][1] = *(const bf16x8*)&Kc[(nt * 16 + lq) * LDK + 32 + quad * 8];
        }
#pragma unroll
        for (int s = 0; s < 2; s++) {
            const unsigned int wq = (s ? w1 : w0) >> (quad * 4);
#pragma unroll
            for (int nt = 0; nt < 2; nt++) {
                f32x4 z = {};
                z = __builtin_amdgcn_mfma_f32_16x16x32_bf16(kf[nt][0], qf[s][0], z, 0, 0, 0);
                z = __builtin_amdgcn_mfma_f32_16x16x32_bf16(kf[nt][1], qf[s][1], z, 0, 0, 0);
                bf16x4 pk;
#pragma unroll
                for (int r = 0; r < 4; r++) {
                    float sv = ((wq >> (nt * 16 + r)) & 1) ? z[r] * 0.125f : -1e9f;
                    float p = __expf(sv);
                    lsum[s] += p;
                    pk[r] = (bf16_t)p;
                }
                *(bf16x4*)&pb[(s * 16 + lq) * LDP + nt * 16 + quad * 4] = pk;
            }
        }

        bf16x8 vf[4];
#pragma unroll
        for (int dt = 0; dt < 4; dt++)
            vf[dt] = *(const bf16x8*)&Vc[(dt * 16 + lq) * LDV + quad * 8];
#pragma unroll
        for (int s = 0; s < 2; s++) {
            bf16x8 pf = *(const bf16x8*)&pb[(s * 16 + lq) * LDP + quad * 8];
#pragma unroll
            for (int dt = 0; dt < 4; dt++)
                o[s][dt] = __builtin_amdgcn_mfma_f32_16x16x32_bf16(pf, vf[dt], o[s][dt], 0, 0, 0);
        }
        __syncthreads();
    }

    // epilogue: reduce l over quads, store O/l
#pragma unroll
    for (int s = 0; s < 2; s++) {
        lsum[s] += __shfl_xor(lsum[s], 16);
        lsum[s] += __shfl_xor(lsum[s], 32);
    }
#pragma unroll
    for (int s = 0; s < 2; s++)
#pragma unroll
        for (int dt = 0; dt < 4; dt++)
#pragma unroll
            for (int r = 0; r < 4; r++) {
                float lv = __shfl(lsum[s], quad * 4 + r);
                float rl = (lv > 0.f) ? 1.0f / lv : 0.f;
                int qrow = qw + s * 16 + quad * 4 + r;
                X[((size_t)(b * 2048) + qrow) * 1024 + h * 64 + dt * 16 + lq] =
                    (bf16_t)(o[s][dt][r] * rl);
            }
}

// ---------------------------------------------------------------------------
extern "C" void kernel_launch(void* const* d_in, const int* in_sizes, int n_in,
                              void* d_out, int out_size, void* d_ws, size_t ws_size,
                              hipStream_t stream)
{
    const float* query  = (const float*)d_in[0];
    const float* key_in = (const float*)d_in[1];
    const float* value  = (const float*)d_in[2];
    const int*   mask   = (const int*)d_in[3];

    char* ws = (char*)d_ws;
    const size_t SZ  = (size_t)8192 * 1024 * 2;  // one [8192,1024] bf16 buffer
    const size_t MPK = (size_t)2 * 1024 * 1024;  // packed mask bits
    bf16_t* Qb  = (bf16_t*)(ws);
    bf16_t* Kb  = (bf16_t*)(ws + SZ);
    bf16_t* Vtb = (bf16_t*)(ws + 2 * SZ);
    bf16_t* Xb  = (bf16_t*)(ws + 3 * SZ);
    unsigned long long* mpack = (unsigned long long*)(ws + 4 * SZ);
    bf16_t* Wc = (bf16_t*)(ws + 4 * SZ + MPK);   // 4 contiguous 1M-elem weights

    const size_t NEED = 4 * SZ + MPK + (size_t)4 * 1048576 * 2;
    if (ws_size < NEED) return;

    wconvert_kernel<<<2048, 256, 0, stream>>>(
        (const float*)d_in[4], (const float*)d_in[6],
        (const float*)d_in[8], (const float*)d_in[10], Wc);
    pack_mask_kernel<<<65536, 256, 0, stream>>>(mask, mpack);

    qkv_gemm<<<dim3(64, 8, 3), 256, 0, stream>>>(
        query, key_in, value, Wc,
        (const float*)d_in[5], (const float*)d_in[7], (const float*)d_in[9],
        Qb, Kb, Vtb);

    attn_kernel<<<dim3(16, 64), 256, 0, stream>>>(Qb, Kb, Vtb,
                                                  (const unsigned int*)mpack, Xb);

    gemm_o<<<dim3(64, 8), 256, 0, stream>>>(Xb, Wc + (size_t)3 * 1048576,
                                            (const float*)d_in[11], (float*)d_out);
}